// Round 1
// baseline (1303.805 us; speedup 1.0000x reference)
//
#include <hip/hip_runtime.h>
#include <math.h>

// Mamba block, fp32, chunked parallel scan.
// k1: per-(b,chunk) compute features + local scan -> (P, H) per (d,s)
// k2: combine chunk partials sequentially -> Hin per chunk
// k3: recompute features, scan from Hin, gate, out_proj, classifier -> logits

namespace {
constexpr int DMODEL = 41;
constexpr int DIN    = 82;     // d_inner
constexpr int NSTATE = 16;
constexpr int DTRANK = 3;
constexpr int NLAB   = 10;
constexpr int BATCH  = 32;
constexpr int SEQ    = 8192;
constexpr int CHUNK  = 512;
constexpr int NCHUNK = SEQ / CHUNK;   // 16
constexpr int TSUB   = 16;            // positions per LDS subtile
constexpr int NSUB   = CHUNK / TSUB;  // 32
constexpr int RWS    = TSUB + 3;      // rows incl. conv halo = 19
constexpr int XPAD   = 44;            // s_x row stride (16B-aligned rows for b128)
constexpr int SPAD   = 83;            // s_xs / s_z row stride
constexpr int CPAD   = 84;            // s_xc row stride (16B-aligned rows)
constexpr int JPAD   = 36;            // s_xdbc row stride: dt@0..2, B@4..19, C@20..35
constexpr int NPH    = BATCH * NCHUNK * DIN * NSTATE;  // 671744 floats per buffer
}

__device__ __forceinline__ float siluf(float v)     { return v / (1.f + expf(-v)); }
__device__ __forceinline__ float softplusf(float v) { return (v > 20.f) ? v : log1pf(expf(v)); }

template <int PASS>  // 1 = partials pass, 3 = final pass
__launch_bounds__(256, 2)
__global__ void mamba_chunk(
    const float* __restrict__ xg,
    const float* __restrict__ w_in,    // (164,41)
    const float* __restrict__ w_conv,  // (82,4)
    const float* __restrict__ b_conv,  // (82)
    const float* __restrict__ w_xproj, // (35,82)
    const float* __restrict__ w_dt,    // (82,3)
    const float* __restrict__ b_dt,    // (82)
    const float* __restrict__ A_log,   // (82,16)
    const float* __restrict__ Dvec,    // (82)
    const float* __restrict__ w_out,   // (41,82)
    const float* __restrict__ w_cls,   // (10,41)
    const float* __restrict__ b_cls,   // (10)
    float* __restrict__ Pg,            // (B,NCHUNK,82,16)  [PASS1 out]
    float* __restrict__ Hg,            // (B,NCHUNK,82,16)  [PASS1 out]
    const float* __restrict__ Hin,     // (B,NCHUNK,82,16)  [PASS3 in]
    float* __restrict__ outg)          // (B,L,10)          [PASS3 out]
{
  __shared__ float s_x[RWS * XPAD];      //  836  raw input rows (pos p0-3 .. p0+15)
  __shared__ float s_xs[RWS * SPAD];     // 1577  xs rows; later aliased as delta[16][SPAD], then y
  __shared__ float s_xc[TSUB * CPAD];    // 1344  conv+silu output; later gated value g
  __shared__ float s_z[TSUB * SPAD];     // 1328  gate branch (PASS3)
  __shared__ float s_xdbc[TSUB * JPAD];  //  576  dt/B/C; later logits buffer
  __shared__ float w_in_t[DMODEL * 164]; // 6724  [k][e] transposed
  __shared__ float w_xp_t[DIN * 35];     // 2870  [dd][j] transposed
  __shared__ float s_cw[DIN * 4];
  __shared__ float s_cb[DIN];
  __shared__ float s_dtw[DIN * DTRANK];
  __shared__ float s_dtb[DIN];
  // total: 63,972 bytes

  const int tid = threadIdx.x;
  const int b   = blockIdx.x / NCHUNK;
  const int c   = blockIdx.x % NCHUNK;
  const int l0c = c * CHUNK;
  constexpr int NE = (PASS == 3) ? 164 : DIN;  // in_proj rows needed
  constexpr int NJ = (PASS == 3) ? 35 : 19;    // x_proj rows needed (PASS1 skips C)

  // ---- weight staging ----
  for (int i = tid; i < DMODEL * 164; i += 256) {
    int k = i / 164, e = i - k * 164;
    w_in_t[i] = w_in[e * DMODEL + k];
  }
  for (int i = tid; i < DIN * 35; i += 256) {
    int dd = i / 35, j = i - dd * 35;
    w_xp_t[i] = w_xproj[j * DIN + dd];
  }
  for (int i = tid; i < DIN * 4; i += 256) s_cw[i] = w_conv[i];
  for (int i = tid; i < DIN * DTRANK; i += 256) s_dtw[i] = w_dt[i];
  if (tid < DIN) { s_cb[tid] = b_conv[tid]; s_dtb[tid] = b_dt[tid]; }

  // ---- per-thread scan state (threads 0..81 own channel d = tid) ----
  float h[NSTATE], Pp[NSTATE], As[NSTATE];
  float A0 = -1.f, Dd = 0.f;
  bool structured = true;
  if (tid < DIN) {
#pragma unroll
    for (int s = 0; s < NSTATE; ++s) As[s] = -expf(A_log[tid * NSTATE + s]);
    A0 = As[0];
#pragma unroll
    for (int s = 0; s < NSTATE; ++s)
      structured = structured &&
        (fabsf(As[s] - (float)(s + 1) * A0) <= 1e-3f * (float)(s + 1) * fabsf(A0));
    structured = structured && (A0 < 0.f);
    if (PASS == 3) {
      Dd = Dvec[tid];
      size_t base = ((size_t)(b * NCHUNK + c)) * (DIN * NSTATE) + (size_t)tid * NSTATE;
#pragma unroll
      for (int s = 0; s < NSTATE; ++s) h[s] = Hin[base + s];
    } else {
#pragma unroll
      for (int s = 0; s < NSTATE; ++s) { h[s] = 0.f; Pp[s] = 1.f; }
    }
  }
  __syncthreads();

  for (int t = 0; t < NSUB; ++t) {
    const int p0 = l0c + t * TSUB;

    // ---- stage 1: load raw x rows p0-3 .. p0+TSUB-1 ----
    for (int i = tid; i < RWS * DMODEL; i += 256) {
      int r = i / DMODEL, k = i - r * DMODEL;
      int pos = p0 - 3 + r;
      s_x[r * XPAD + k] =
          (pos >= 0) ? xg[(size_t)b * SEQ * DMODEL + (size_t)pos * DMODEL + k] : 0.f;
    }
    __syncthreads();

    // ---- stage 2: in_proj (xs rows incl halo; z rows for PASS3) ----
    {
      const int e = tid;
      if (e < NE) {
        float acc[RWS];
#pragma unroll
        for (int r = 0; r < RWS; ++r) acc[r] = 0.f;
#pragma unroll
        for (int kq = 0; kq < 40; kq += 4) {
          const float w0 = w_in_t[(kq + 0) * 164 + e];
          const float w1 = w_in_t[(kq + 1) * 164 + e];
          const float w2 = w_in_t[(kq + 2) * 164 + e];
          const float w3 = w_in_t[(kq + 3) * 164 + e];
#pragma unroll
          for (int r = 0; r < RWS; ++r) {
            const float4 xv = *(const float4*)&s_x[r * XPAD + kq];
            acc[r] = fmaf(xv.x, w0, acc[r]);
            acc[r] = fmaf(xv.y, w1, acc[r]);
            acc[r] = fmaf(xv.z, w2, acc[r]);
            acc[r] = fmaf(xv.w, w3, acc[r]);
          }
        }
        const float wl = w_in_t[40 * 164 + e];
#pragma unroll
        for (int r = 0; r < RWS; ++r) acc[r] = fmaf(s_x[r * XPAD + 40], wl, acc[r]);
        if (e < DIN) {
#pragma unroll
          for (int r = 0; r < RWS; ++r) s_xs[r * SPAD + e] = acc[r];
        } else {
#pragma unroll
          for (int r = 3; r < RWS; ++r) s_z[(r - 3) * SPAD + (e - DIN)] = acc[r];
        }
      }
    }
    __syncthreads();

    // ---- stage 3: causal conv (4 taps) + silu ----
    for (int w = tid; w < TSUB * DIN; w += 256) {
      const int l = w & 15, e = w >> 4;
      float a = s_cb[e];
#pragma unroll
      for (int k = 0; k < 4; ++k) a = fmaf(s_xs[(l + k) * SPAD + e], s_cw[e * 4 + k], a);
      s_xc[l * CPAD + e] = siluf(a);
    }
    __syncthreads();

    // ---- stage 4a: x_proj -> dt / B / C ----
    for (int w = tid; w < TSUB * NJ; w += 256) {
      const int l = w & 15, j = w >> 4;
      float a = 0.f;
#pragma unroll
      for (int dq = 0; dq < 80; dq += 4) {
        const float4 xv = *(const float4*)&s_xc[l * CPAD + dq];
        a = fmaf(xv.x, w_xp_t[(dq + 0) * 35 + j], a);
        a = fmaf(xv.y, w_xp_t[(dq + 1) * 35 + j], a);
        a = fmaf(xv.z, w_xp_t[(dq + 2) * 35 + j], a);
        a = fmaf(xv.w, w_xp_t[(dq + 3) * 35 + j], a);
      }
      a = fmaf(s_xc[l * CPAD + 80], w_xp_t[80 * 35 + j], a);
      a = fmaf(s_xc[l * CPAD + 81], w_xp_t[81 * 35 + j], a);
      const int col = (j < DTRANK) ? j : j + 1;
      s_xdbc[l * JPAD + col] = a;
    }
    __syncthreads();

    // ---- stage 4b: delta = softplus(dt @ w_dt^T + b_dt) -> into s_xs rows 0..15 ----
    for (int w = tid; w < TSUB * DIN; w += 256) {
      const int l = w & 15, d = w >> 4;
      float a = s_dtb[d];
      a = fmaf(s_xdbc[l * JPAD + 0], s_dtw[d * 3 + 0], a);
      a = fmaf(s_xdbc[l * JPAD + 1], s_dtw[d * 3 + 1], a);
      a = fmaf(s_xdbc[l * JPAD + 2], s_dtw[d * 3 + 2], a);
      s_xs[l * SPAD + d] = softplusf(a);
    }
    __syncthreads();

    // ---- stage 5: selective scan ----
    if (tid < DIN) {
      const int d = tid;
#pragma unroll 1
      for (int l = 0; l < TSUB; ++l) {
        const float dl  = s_xs[l * SPAD + d];
        const float xcd = s_xc[l * CPAD + d];
        const float dxc = dl * xcd;
        const float4 B0 = *(const float4*)&s_xdbc[l * JPAD + 4];
        const float4 B1 = *(const float4*)&s_xdbc[l * JPAD + 8];
        const float4 B2 = *(const float4*)&s_xdbc[l * JPAD + 12];
        const float4 B3 = *(const float4*)&s_xdbc[l * JPAD + 16];
        const float Bv[NSTATE] = {B0.x, B0.y, B0.z, B0.w, B1.x, B1.y, B1.z, B1.w,
                                  B2.x, B2.y, B2.z, B2.w, B3.x, B3.y, B3.z, B3.w};
        float Cv[NSTATE];
        if (PASS == 3) {
          const float4 C0 = *(const float4*)&s_xdbc[l * JPAD + 20];
          const float4 C1 = *(const float4*)&s_xdbc[l * JPAD + 24];
          const float4 C2 = *(const float4*)&s_xdbc[l * JPAD + 28];
          const float4 C3 = *(const float4*)&s_xdbc[l * JPAD + 32];
          Cv[0]=C0.x; Cv[1]=C0.y; Cv[2]=C0.z; Cv[3]=C0.w;
          Cv[4]=C1.x; Cv[5]=C1.y; Cv[6]=C1.z; Cv[7]=C1.w;
          Cv[8]=C2.x; Cv[9]=C2.y; Cv[10]=C2.z; Cv[11]=C2.w;
          Cv[12]=C3.x; Cv[13]=C3.y; Cv[14]=C3.z; Cv[15]=C3.w;
        }
        float y = (PASS == 3) ? Dd * xcd : 0.f;
        if (structured) {  // A[s] == (s+1)*A0: dA_s = q^(s+1), one exp per (l,d)
          const float q = expf(dl * A0);
          float e = q;
#pragma unroll
          for (int s = 0; s < NSTATE; ++s) {
            h[s] = fmaf(e, h[s], dxc * Bv[s]);
            if (PASS == 1) Pp[s] *= e; else y = fmaf(h[s], Cv[s], y);
            if (s < NSTATE - 1) e *= q;
          }
        } else {           // generic fallback
#pragma unroll
          for (int s = 0; s < NSTATE; ++s) {
            const float e = expf(dl * As[s]);
            h[s] = fmaf(e, h[s], dxc * Bv[s]);
            if (PASS == 1) Pp[s] *= e; else y = fmaf(h[s], Cv[s], y);
          }
        }
        if (PASS == 3) s_xs[l * SPAD + d] = y;  // overwrite consumed delta slot
      }
    }
    __syncthreads();

    if (PASS == 3) {
      // ---- stage 6a: gate g = y * silu(z) -> into s_xc ----
      for (int w = tid; w < TSUB * DIN; w += 256) {
        const int l = w & 15, d = w >> 4;
        s_xc[l * CPAD + d] = s_xs[l * SPAD + d] * siluf(s_z[l * SPAD + d]);
      }
      __syncthreads();
      // ---- stage 6b: out_proj (41x82), weights from global/L1 ----
      for (int w = tid; w < TSUB * DMODEL; w += 256) {
        const int l = w & 15, dm = w >> 4;
        const float2* wp = (const float2*)(w_out + dm * DIN);
        const float2* gp = (const float2*)&s_xc[l * CPAD];
        float a = 0.f;
#pragma unroll
        for (int dq = 0; dq < 41; ++dq) {
          const float2 wv = wp[dq];
          const float2 gv = gp[dq];
          a = fmaf(wv.x, gv.x, a);
          a = fmaf(wv.y, gv.y, a);
        }
        s_x[l * XPAD + dm] = a;  // s_x free after stage 2
      }
      __syncthreads();
      // ---- stage 6c: classifier (10x41) ----
      for (int w = tid; w < TSUB * NLAB; w += 256) {
        const int l = w & 15, n = w >> 4;
        float a = b_cls[n];
#pragma unroll
        for (int dm = 0; dm < DMODEL; ++dm) a = fmaf(w_cls[n * DMODEL + dm], s_x[l * XPAD + dm], a);
        s_xdbc[l * NLAB + n] = a;  // s_xdbc free after scan
      }
      __syncthreads();
      // ---- contiguous store of 160 logits ----
      for (int i = tid; i < TSUB * NLAB; i += 256)
        outg[((size_t)(b * SEQ + p0)) * NLAB + i] = s_xdbc[i];
      __syncthreads();
    }
  }

  if (PASS == 1 && tid < DIN) {
    size_t base = ((size_t)(b * NCHUNK + c)) * (DIN * NSTATE) + (size_t)tid * NSTATE;
#pragma unroll
    for (int s = 0; s < NSTATE; ++s) { Pg[base + s] = Pp[s]; Hg[base + s] = h[s]; }
  }
}

__global__ __launch_bounds__(256) void mamba_combine(
    const float* __restrict__ P, const float* __restrict__ H, float* __restrict__ Hin) {
  const int g  = blockIdx.x * 256 + threadIdx.x;  // 0..41983
  const int b  = g / (DIN * NSTATE);
  const int ds = g - b * (DIN * NSTATE);
  float h = 0.f;
#pragma unroll 1
  for (int c = 0; c < NCHUNK; ++c) {
    const size_t idx = ((size_t)(b * NCHUNK + c)) * (DIN * NSTATE) + ds;
    Hin[idx] = h;
    h = fmaf(P[idx], h, H[idx]);
  }
}

extern "C" void kernel_launch(void* const* d_in, const int* in_sizes, int n_in,
                              void* d_out, int out_size, void* d_ws, size_t ws_size,
                              hipStream_t stream) {
  const float* xg     = (const float*)d_in[0];
  const float* w_in   = (const float*)d_in[1];
  const float* w_conv = (const float*)d_in[2];
  const float* b_conv = (const float*)d_in[3];
  const float* w_xp   = (const float*)d_in[4];
  const float* w_dt   = (const float*)d_in[5];
  const float* b_dt   = (const float*)d_in[6];
  const float* A_log  = (const float*)d_in[7];
  const float* Dv     = (const float*)d_in[8];
  const float* w_out  = (const float*)d_in[9];
  const float* w_cls  = (const float*)d_in[10];
  const float* b_cls  = (const float*)d_in[11];

  float* Pg   = (float*)d_ws;          // 671744 floats
  float* Hg   = Pg + NPH;              // 671744 floats
  float* Hin  = Hg + NPH;              // 671744 floats (8.06 MB total)
  float* outg = (float*)d_out;

  dim3 grid(BATCH * NCHUNK), blk(256);
  mamba_chunk<1><<<grid, blk, 0, stream>>>(xg, w_in, w_conv, b_conv, w_xp, w_dt, b_dt,
                                           A_log, Dv, w_out, w_cls, b_cls,
                                           Pg, Hg, nullptr, nullptr);
  mamba_combine<<<dim3((BATCH * DIN * NSTATE) / 256), blk, 0, stream>>>(Pg, Hg, Hin);
  mamba_chunk<3><<<grid, blk, 0, stream>>>(xg, w_in, w_conv, b_conv, w_xp, w_dt, b_dt,
                                           A_log, Dv, w_out, w_cls, b_cls,
                                           nullptr, nullptr, Hin, outg);
}